// Round 6
// baseline (87.038 us; speedup 1.0000x reference)
//
#include <hip/hip_runtime.h>

#define N_POINTS   65536
#define N_ANCHORS  1024
#define MAX_PTS    512
#define APB        4                    // anchors per block
#define NBLK       (N_ANCHORS / APB)    // 256 blocks = 1 per CU
#define NTHR       1024                 // 16 waves -> 4 waves/SIMD latency hiding
#define CAPB       512                  // LDS survivors/anchor (mean ~59, max ~210)

// Single fused kernel, brute-force scan. No binning: the rank-by-original-index
// epilogue makes append order irrelevant, so the scan loop has NO barriers and
// loads pipeline freely (R1's 155us came from 256 barrier'd chunks, not the
// 67M tests: VALU floor for the tests is ~9us).
__global__ __launch_bounds__(NTHR) void fused_scan_kernel(
    const float* __restrict__ points,   // (N_POINTS, 3)
    const float* __restrict__ anchors,  // (N_ANCHORS, 6)
    float* __restrict__ out,            // (N_ANCHORS, MAX_PTS, 3)
    float* __restrict__ counts)         // (N_ANCHORS,) as float values
{
    const int b   = blockIdx.x;
    const int tid = threadIdx.x;

    // 4 anchors' params in registers (identical fp32 ops to reference)
    float xmin[APB], xmax[APB], ymin[APB], ymax[APB], hh[APB], acx[APB], acy[APB];
    #pragma unroll
    for (int j = 0; j < APB; ++j) {
        const int a = b * APB + j;
        acx[j] = anchors[a * 6 + 0];
        acy[j] = anchors[a * 6 + 1];
        const float hw = anchors[a * 6 + 3] * 0.5f;
        const float hl = anchors[a * 6 + 4] * 0.5f;
        hh[j]  = anchors[a * 6 + 5];
        xmin[j] = acx[j] - hw; xmax[j] = acx[j] + hw;
        ymin[j] = acy[j] - hl; ymax[j] = acy[j] + hl;
    }

    __shared__ float4 buf[APB][CAPB];   // (x, y, z, asfloat(orig_idx))
    __shared__ int k[APB];
    if (tid < APB) k[tid] = 0;
    __syncthreads();

    // scan: 4 points per thread-iteration via 3 float4 loads (48B, b128)
    const float4* __restrict__ pts4 = (const float4*)points;
    for (int it = 0; it < N_POINTS / 4 / NTHR; ++it) {   // 16 iterations
        const int g = it * NTHR + tid;                   // group of 4 points
        const float4 A = pts4[g * 3 + 0];
        const float4 B = pts4[g * 3 + 1];
        const float4 C = pts4[g * 3 + 2];
        const float px[4] = {A.x, A.w, B.z, C.y};
        const float py[4] = {A.y, B.x, B.w, C.z};
        const float pz[4] = {A.z, B.y, C.x, C.w};
        #pragma unroll
        for (int m = 0; m < 4; ++m) {
            const int p = g * 4 + m;
            #pragma unroll
            for (int j = 0; j < APB; ++j) {
                if (px[m] >= xmin[j] && px[m] <= xmax[j] &&
                    py[m] >= ymin[j] && py[m] <= ymax[j] &&
                    pz[m] >= 0.0f && pz[m] <= hh[j]) {
                    const int slot = atomicAdd(&k[j], 1);   // LDS atomic, rare
                    if (slot < CAPB)
                        buf[j][slot] =
                            make_float4(px[m], py[m], pz[m], __int_as_float(p));
                }
            }
        }
    }
    __syncthreads();

    // epilogue: exact first-n semantics via rank of original index
    #pragma unroll
    for (int j = 0; j < APB; ++j) {
        const int a  = b * APB + j;
        const int K  = k[j];                    // exact uncapped inside-count
        const int Kc = K < CAPB ? K : CAPB;     // K>CAPB is +27 sigma: impossible
        float* __restrict__ outa = out + (size_t)a * (MAX_PTS * 3);

        for (int e = tid; e < Kc; e += NTHR) {
            const float4 pe = buf[j][e];
            const int ide = __float_as_int(pe.w);
            int rank = 0;
            for (int f = 0; f < Kc; ++f)
                rank += (__float_as_int(buf[j][f].w) < ide) ? 1 : 0;
            if (rank < MAX_PTS) {
                outa[rank * 3 + 0] = pe.x - acx[j];
                outa[rank * 3 + 1] = pe.y - acy[j];
                outa[rank * 3 + 2] = pe.z;      // center z = 0
            }
        }
        // ranks fill [0, min(K,512)) contiguously; zero the poisoned tail
        const int filled = (K < MAX_PTS ? K : MAX_PTS) * 3;
        for (int i = filled + tid; i < MAX_PTS * 3; i += NTHR) outa[i] = 0.0f;

        if (tid == 0) counts[a] = (float)K;     // whole d_out read back as f32
    }
}

extern "C" void kernel_launch(void* const* d_in, const int* in_sizes, int n_in,
                              void* d_out, int out_size, void* d_ws, size_t ws_size,
                              hipStream_t stream) {
    const float* points  = (const float*)d_in[0];
    const float* anchors = (const float*)d_in[1];

    float* out    = (float*)d_out;                               // (1024,512,3)
    float* counts = (float*)d_out + (size_t)N_ANCHORS * MAX_PTS * 3;

    // single node, no workspace, no memset
    fused_scan_kernel<<<dim3(NBLK), dim3(NTHR), 0, stream>>>(
        points, anchors, out, counts);
}

// Round 7
// 68.512 us; speedup vs baseline: 1.2704x; 1.2704x over previous
//
#include <hip/hip_runtime.h>

#define N_POINTS  65536
#define N_ANCHORS 1024
#define MAX_PTS   512
#define GX        20             // 20x20 grid, cell = 5.0 (>= max box span of 5.0)
#define NC        (GX * GX)      // 400 cells
#define INV_CS    0.2f
#define NSUB      16             // scatter blocks; each bins a disjoint 4096-pt slice
#define CAPS      48             // per (cell,sub) capacity: mean 10.2, +11.8 sigma
#define LDS_CAP   512            // survivors/anchor (max box 5x5 -> ~164 mean, ~230 max)

// ws layout (bytes) — NOTHING needs pre-zeroing (no memset node):
//   0      : int cnt[NC * NSUB]                 (fully written by scatter_kernel)
//   32768  : float4 binned[NC * NSUB * CAPS]    (x,y,z,asfloat(idx)) = 4.9 MB
#define WS_CNT    0
#define WS_BINNED 32768

__device__ __forceinline__ int cell_of(float px, float py) {
    int cx = (int)(px * INV_CS);            // coords in [0,100): trunc == floor
    int cy = (int)(py * INV_CS);
    cx = cx > GX - 1 ? GX - 1 : cx;
    cy = cy > GX - 1 ? GX - 1 : cy;
    return cy * GX + cx;
}

// 16 blocks x 1024 thr; block b owns points [b*4096, (b+1)*4096) — exactly one
// vectorized round: each thread takes 4 points via 3 float4 (b128) loads.
// LDS counters (zeroed in-kernel) -> no global atomics, no pre-zeroed state.
// Order within a (cell,sub) segment is irrelevant; anchor re-derives exact
// first-n order by ranking original indices.
__global__ __launch_bounds__(1024) void scatter_kernel(
    const float* __restrict__ points, int* __restrict__ cnt,
    float4* __restrict__ binned)
{
    __shared__ int lcnt[NC];
    const int b   = blockIdx.x;
    const int tid = threadIdx.x;

    if (tid < NC) lcnt[tid] = 0;
    __syncthreads();

    const int g = b * 1024 + tid;           // group of 4 points
    const float4* __restrict__ pts4 = (const float4*)points;
    const float4 A = pts4[g * 3 + 0];
    const float4 B = pts4[g * 3 + 1];
    const float4 C = pts4[g * 3 + 2];
    const float px[4] = {A.x, A.w, B.z, C.y};
    const float py[4] = {A.y, B.x, B.w, C.z};
    const float pz[4] = {A.z, B.y, C.x, C.w};
    #pragma unroll
    for (int m = 0; m < 4; ++m) {
        const int c    = cell_of(px[m], py[m]);
        const int slot = atomicAdd(&lcnt[c], 1);      // LDS atomic
        if (slot < CAPS)   // statistically impossible to exceed; guard anyway
            binned[(c * NSUB + b) * CAPS + slot] =
                make_float4(px[m], py[m], pz[m], __int_as_float(g * 4 + m));
    }
    __syncthreads();
    if (tid < NC) {
        int l = lcnt[tid];
        cnt[tid * NSUB + b] = l < CAPS ? l : CAPS;
    }
}

// One block (256 thr) per anchor. Box spans <=2 cells/axis -> <=4 cells x 16
// subs = 64 segments. Direct mapping: 4 threads per segment (group = tid>>2),
// no per-candidate search, no prefix scan. Survivors appended to LDS via
// atomic; slot = rank of original index (exact first-n, any append order).
__global__ __launch_bounds__(256) void anchor_kernel(
    const float4* __restrict__ binned, const int* __restrict__ cnt,
    const float* __restrict__ anchors, float* __restrict__ out,
    float* __restrict__ counts)
{
    const int a   = blockIdx.x;
    const int tid = threadIdx.x;

    const float acx = anchors[a * 6 + 0];
    const float acy = anchors[a * 6 + 1];
    const float hw  = anchors[a * 6 + 3] * 0.5f;   // identical fp32 ops to ref
    const float hl  = anchors[a * 6 + 4] * 0.5f;
    const float h   = anchors[a * 6 + 5];
    const float xmin = acx - hw, xmax = acx + hw;
    const float ymin = acy - hl, ymax = acy + hl;

    // covered cell range (cell_of is monotone; coords in [0,100))
    int cx0 = (int)(fmaxf(xmin, 0.0f) * INV_CS);
    int cx1 = (int)(fmaxf(xmax, 0.0f) * INV_CS);
    int cy0 = (int)(fmaxf(ymin, 0.0f) * INV_CS);
    int cy1 = (int)(fmaxf(ymax, 0.0f) * INV_CS);
    if (cx1 > GX - 1) cx1 = GX - 1;
    if (cy1 > GX - 1) cy1 = GX - 1;
    if (cx0 > GX - 1) cx0 = GX - 1;
    if (cy0 > GX - 1) cy0 = GX - 1;

    const int cell0 = cy0 * GX + cx0;
    const int cell1 = cy0 * GX + cx1;
    const int cell2 = cy1 * GX + cx0;
    const int cell3 = cy1 * GX + cx1;
    int ncells = 1;
    if (cx1 > cx0) ncells = 2;
    if (cy1 > cy0) ncells = (cx1 > cx0) ? 4 : 2;

    __shared__ int segLen[4 * NSUB];
    __shared__ int segBase[4 * NSUB];
    __shared__ int k;
    __shared__ float4 buf[LDS_CAP];

    if (tid < 4 * NSUB) {
        const int q   = tid >> 4;          // cell slot 0..3
        const int sub = tid & (NSUB - 1);
        int len = 0, base = 0;
        if (q < ncells) {
            int ci;
            if (ncells == 1)      ci = cell0;
            else if (ncells == 2) ci = (q == 0) ? cell0 : ((cx1 > cx0) ? cell1 : cell2);
            else                  ci = (q == 0) ? cell0 : (q == 1) ? cell1
                                     : (q == 2) ? cell2 : cell3;
            len  = cnt[ci * NSUB + sub];             // already clamped to CAPS
            base = (ci * NSUB + sub) * CAPS;
        }
        segLen[tid]  = len;
        segBase[tid] = base;
    }
    if (tid == 0) k = 0;
    __syncthreads();

    // 64 groups of 4 threads, group g scans segment g directly
    const int grp   = tid >> 2;
    const int lane4 = tid & 3;
    const int len   = segLen[grp];
    const int base  = segBase[grp];
    for (int e = lane4; e < len; e += 4) {
        const float4 p = binned[base + e];
        if (p.x >= xmin && p.x <= xmax &&
            p.y >= ymin && p.y <= ymax &&
            p.z >= 0.0f && p.z <= h) {
            const int slot = atomicAdd(&k, 1);
            if (slot < LDS_CAP) buf[slot] = p;
        }
    }
    __syncthreads();

    const int K  = k;                       // exact uncapped inside-count
    const int Kc = K < LDS_CAP ? K : LDS_CAP;   // max ~230 << 512

    float* __restrict__ outa = out + (size_t)a * (MAX_PTS * 3);

    for (int e = tid; e < Kc; e += 256) {
        const float4 pe = buf[e];
        const int ide = __float_as_int(pe.w);
        int rank = 0;
        for (int f = 0; f < Kc; ++f)
            rank += (__float_as_int(buf[f].w) < ide) ? 1 : 0;
        if (rank < MAX_PTS) {
            outa[rank * 3 + 0] = pe.x - acx;
            outa[rank * 3 + 1] = pe.y - acy;
            outa[rank * 3 + 2] = pe.z;      // center z = 0
        }
    }

    // ranks fill [0, min(K,512)) contiguously; zero the poisoned tail
    const int filled = (K < MAX_PTS ? K : MAX_PTS) * 3;
    for (int i = filled + tid; i < MAX_PTS * 3; i += 256) outa[i] = 0.0f;

    if (tid == 0) counts[a] = (float)K;     // whole d_out read back as f32
}

extern "C" void kernel_launch(void* const* d_in, const int* in_sizes, int n_in,
                              void* d_out, int out_size, void* d_ws, size_t ws_size,
                              hipStream_t stream) {
    const float* points  = (const float*)d_in[0];
    const float* anchors = (const float*)d_in[1];

    float* out    = (float*)d_out;                               // (1024,512,3)
    float* counts = (float*)d_out + (size_t)N_ANCHORS * MAX_PTS * 3;

    char* ws = (char*)d_ws;
    int*    cnt    = (int*)(ws + WS_CNT);
    float4* binned = (float4*)(ws + WS_BINNED);

    // 2 nodes, no memset: cnt is fully written by scatter_kernel.
    scatter_kernel<<<dim3(NSUB),      dim3(1024), 0, stream>>>(points, cnt, binned);
    anchor_kernel <<<dim3(N_ANCHORS), dim3(256),  0, stream>>>(binned, cnt, anchors, out, counts);
}

// Round 8
// 67.364 us; speedup vs baseline: 1.2921x; 1.0170x over previous
//
#include <hip/hip_runtime.h>

#define N_POINTS  65536
#define N_ANCHORS 1024
#define MAX_PTS   512
#define GX        20             // 20x20 grid, cell = 5.0 (>= max box span of 5.0)
#define NC        (GX * GX)      // 400 cells
#define INV_CS    0.2f
#define NSUB      16             // scatter blocks; each bins a disjoint 4096-pt slice
#define CAPS      48             // per (cell,sub) capacity: mean 10.2, +11.8 sigma (proven R7)
#define LDS_CAP   512            // survivors/anchor (max ~230)

// ws layout (bytes) — NOTHING needs pre-zeroing (no memset node):
//   0      : int cnt[NC * NSUB]                 (fully written by scatter_kernel)
//   32768  : float4 binned[NC * NSUB * CAPS]    (x,y,z,asfloat(idx)) = 4.9 MB
#define WS_CNT    0
#define WS_BINNED 32768

__device__ __forceinline__ int cell_of(float px, float py) {
    int cx = (int)(px * INV_CS);            // coords in [0,100): trunc == floor
    int cy = (int)(py * INV_CS);
    cx = cx > GX - 1 ? GX - 1 : cx;
    cy = cy > GX - 1 ? GX - 1 : cy;
    return cy * GX + cx;
}

// 16 blocks x 1024 thr; block b owns points [b*4096, (b+1)*4096) — exactly one
// vectorized round: each thread takes 4 points via 3 float4 (b128) loads.
// LDS counters (zeroed in-kernel) -> no global atomics, no pre-zeroed state.
// Order within a (cell,sub) segment is irrelevant; anchor re-derives exact
// first-n order by ranking original indices.
__global__ __launch_bounds__(1024) void scatter_kernel(
    const float* __restrict__ points, int* __restrict__ cnt,
    float4* __restrict__ binned)
{
    __shared__ int lcnt[NC];
    const int b   = blockIdx.x;
    const int tid = threadIdx.x;

    if (tid < NC) lcnt[tid] = 0;
    __syncthreads();

    const int g = b * 1024 + tid;           // group of 4 points
    const float4* __restrict__ pts4 = (const float4*)points;
    const float4 A = pts4[g * 3 + 0];
    const float4 B = pts4[g * 3 + 1];
    const float4 C = pts4[g * 3 + 2];
    const float px[4] = {A.x, A.w, B.z, C.y};
    const float py[4] = {A.y, B.x, B.w, C.z};
    const float pz[4] = {A.z, B.y, C.x, C.w};
    #pragma unroll
    for (int m = 0; m < 4; ++m) {
        const int c    = cell_of(px[m], py[m]);
        const int slot = atomicAdd(&lcnt[c], 1);      // LDS atomic
        if (slot < CAPS)   // statistically impossible to exceed; guard anyway
            binned[(c * NSUB + b) * CAPS + slot] =
                make_float4(px[m], py[m], pz[m], __int_as_float(g * 4 + m));
    }
    __syncthreads();
    if (tid < NC) {
        int l = lcnt[tid];
        cnt[tid * NSUB + b] = l < CAPS ? l : CAPS;
    }
}

// One block (256 thr) per anchor. Box spans <=2 cells/axis -> <=4 cells x 16
// subs = 64 segments; 4 threads per segment, no search, no prefix scan.
// Full output tile is zeroed with float4 stores BEFORE the candidate scan so
// the stores overlap the scattered L2 candidate-load latency; the post-scan
// __syncthreads (vmcnt(0) drain) orders zeros before the survivor writes.
// Survivors appended to LDS via atomic; slot = rank of original index (exact
// first-n semantics regardless of append order).
__global__ __launch_bounds__(256) void anchor_kernel(
    const float4* __restrict__ binned, const int* __restrict__ cnt,
    const float* __restrict__ anchors, float* __restrict__ out,
    float* __restrict__ counts)
{
    const int a   = blockIdx.x;
    const int tid = threadIdx.x;

    const float acx = anchors[a * 6 + 0];
    const float acy = anchors[a * 6 + 1];
    const float hw  = anchors[a * 6 + 3] * 0.5f;   // identical fp32 ops to ref
    const float hl  = anchors[a * 6 + 4] * 0.5f;
    const float h   = anchors[a * 6 + 5];
    const float xmin = acx - hw, xmax = acx + hw;
    const float ymin = acy - hl, ymax = acy + hl;

    // zero the full 6 KB tile early (no dependency on the scan; b128 stores)
    float* __restrict__ outa = out + (size_t)a * (MAX_PTS * 3);
    float4* __restrict__ outa4 = (float4*)outa;     // 6144 B stride -> 16B aligned
    const float4 z4 = make_float4(0.f, 0.f, 0.f, 0.f);
    #pragma unroll
    for (int r = 0; r < (MAX_PTS * 3 / 4) / 256; ++r)   // 384 stores, 2 rounds
        outa4[r * 256 + tid] = z4;

    // covered cell range (cell_of is monotone; coords in [0,100))
    int cx0 = (int)(fmaxf(xmin, 0.0f) * INV_CS);
    int cx1 = (int)(fmaxf(xmax, 0.0f) * INV_CS);
    int cy0 = (int)(fmaxf(ymin, 0.0f) * INV_CS);
    int cy1 = (int)(fmaxf(ymax, 0.0f) * INV_CS);
    if (cx1 > GX - 1) cx1 = GX - 1;
    if (cy1 > GX - 1) cy1 = GX - 1;
    if (cx0 > GX - 1) cx0 = GX - 1;
    if (cy0 > GX - 1) cy0 = GX - 1;

    const int cell0 = cy0 * GX + cx0;
    const int cell1 = cy0 * GX + cx1;
    const int cell2 = cy1 * GX + cx0;
    const int cell3 = cy1 * GX + cx1;
    int ncells = 1;
    if (cx1 > cx0) ncells = 2;
    if (cy1 > cy0) ncells = (cx1 > cx0) ? 4 : 2;

    __shared__ int segLen[4 * NSUB];
    __shared__ int segBase[4 * NSUB];
    __shared__ int k;
    __shared__ float4 buf[LDS_CAP];

    if (tid < 4 * NSUB) {
        const int q   = tid >> 4;          // cell slot 0..3
        const int sub = tid & (NSUB - 1);
        int len = 0, base = 0;
        if (q < ncells) {
            int ci;
            if (ncells == 1)      ci = cell0;
            else if (ncells == 2) ci = (q == 0) ? cell0 : ((cx1 > cx0) ? cell1 : cell2);
            else                  ci = (q == 0) ? cell0 : (q == 1) ? cell1
                                     : (q == 2) ? cell2 : cell3;
            len  = cnt[ci * NSUB + sub];             // already clamped to CAPS
            base = (ci * NSUB + sub) * CAPS;
        }
        segLen[tid]  = len;
        segBase[tid] = base;
    }
    if (tid == 0) k = 0;
    __syncthreads();

    // 64 groups of 4 threads, group g scans segment g directly
    const int grp   = tid >> 2;
    const int lane4 = tid & 3;
    const int len   = segLen[grp];
    const int base  = segBase[grp];
    for (int e = lane4; e < len; e += 4) {
        const float4 p = binned[base + e];
        if (p.x >= xmin && p.x <= xmax &&
            p.y >= ymin && p.y <= ymax &&
            p.z >= 0.0f && p.z <= h) {
            const int slot = atomicAdd(&k, 1);
            if (slot < LDS_CAP) buf[slot] = p;
        }
    }
    __syncthreads();   // also drains the zero stores (vmcnt(0) before barrier)

    const int K  = k;                       // exact uncapped inside-count
    const int Kc = K < LDS_CAP ? K : LDS_CAP;   // max ~230 << 512

    for (int e = tid; e < Kc; e += 256) {
        const float4 pe = buf[e];
        const int ide = __float_as_int(pe.w);
        int rank = 0;
        for (int f = 0; f < Kc; ++f)        // lockstep LDS reads -> broadcasts
            rank += (__float_as_int(buf[f].w) < ide) ? 1 : 0;
        if (rank < MAX_PTS) {               // ranks are a permutation of 0..K-1
            outa[rank * 3 + 0] = pe.x - acx;
            outa[rank * 3 + 1] = pe.y - acy;
            outa[rank * 3 + 2] = pe.z;      // center z = 0
        }
    }

    if (tid == 0) counts[a] = (float)K;     // whole d_out read back as f32
}

extern "C" void kernel_launch(void* const* d_in, const int* in_sizes, int n_in,
                              void* d_out, int out_size, void* d_ws, size_t ws_size,
                              hipStream_t stream) {
    const float* points  = (const float*)d_in[0];
    const float* anchors = (const float*)d_in[1];

    float* out    = (float*)d_out;                               // (1024,512,3)
    float* counts = (float*)d_out + (size_t)N_ANCHORS * MAX_PTS * 3;

    char* ws = (char*)d_ws;
    int*    cnt    = (int*)(ws + WS_CNT);
    float4* binned = (float4*)(ws + WS_BINNED);

    // 2 nodes, no memset: cnt is fully written by scatter_kernel.
    scatter_kernel<<<dim3(NSUB),      dim3(1024), 0, stream>>>(points, cnt, binned);
    anchor_kernel <<<dim3(N_ANCHORS), dim3(256),  0, stream>>>(binned, cnt, anchors, out, counts);
}